// Round 1
// baseline (298.110 us; speedup 1.0000x reference)
//
#include <hip/hip_runtime.h>

#define B   8
#define C   256
#define N   4096
#define H   8
#define D   64
#define HID 512
#define SCALE 0.125f

typedef __attribute__((ext_vector_type(8))) __bf16 bf16x8;
typedef __attribute__((ext_vector_type(4))) float f32x4;

__device__ __forceinline__ ushort f2bf(float f) {
  union { float f; unsigned u; } v; v.f = f;
  unsigned r = v.u + 0x7FFFu + ((v.u >> 16) & 1u);
  return (ushort)(r >> 16);
}

__device__ __forceinline__ f32x4 mfma16(bf16x8 a, bf16x8 b, f32x4 c) {
  return __builtin_amdgcn_mfma_f32_16x16x32_bf16(a, b, c, 0, 0, 0);
}

// ---------------------------------------------------------------------------
// Cast Wk, Wv to bf16 (row-major [HID][C] kept).
// ---------------------------------------------------------------------------
__global__ __launch_bounds__(256) void cast_w_kernel(
    const float* __restrict__ Wk, const float* __restrict__ Wv,
    ushort* __restrict__ wk_bf, ushort* __restrict__ wv_bf) {
  const int t = (blockIdx.x * 256 + threadIdx.x) * 4;   // HID*C = 131072 elems
  const float4 a = *(const float4*)(Wk + t);
  const float4 b = *(const float4*)(Wv + t);
  ushort4 ra, rb;
  ra.x = f2bf(a.x); ra.y = f2bf(a.y); ra.z = f2bf(a.z); ra.w = f2bf(a.w);
  rb.x = f2bf(b.x); rb.y = f2bf(b.y); rb.z = f2bf(b.z); rb.w = f2bf(b.w);
  *(ushort4*)(wk_bf + t) = ra;
  *(ushort4*)(wv_bf + t) = rb;
}

// ---------------------------------------------------------------------------
// Transpose+cast: src fp32 [b][R][L] -> dst bf16 [b][L][R].  64x64 tiles.
// ---------------------------------------------------------------------------
__global__ __launch_bounds__(256) void transpose_cast_kernel(
    const float* __restrict__ src, ushort* __restrict__ dst, int R, int L) {
  __shared__ float tile[64 * 65];
  const int l0 = blockIdx.x * 64, r0 = blockIdx.y * 64, b = blockIdx.z;
  const int tid = threadIdx.x;
  const int rr = tid >> 4, c4 = (tid & 15) << 2;
  const float* sp = src + ((size_t)b * R + r0) * L + l0;
#pragma unroll
  for (int p = 0; p < 4; ++p) {
    const float4 v = *(const float4*)(sp + (size_t)(rr + p * 16) * L + c4);
    float* tp = tile + (rr + p * 16) * 65 + c4;
    tp[0] = v.x; tp[1] = v.y; tp[2] = v.z; tp[3] = v.w;
  }
  __syncthreads();
  const int lr = tid >> 2, rb = (tid & 3) << 4;
  uint pk[8];
#pragma unroll
  for (int k = 0; k < 16; k += 2) {
    const uint lo = f2bf(tile[(rb + k) * 65 + lr]);
    const uint hi = f2bf(tile[(rb + k + 1) * 65 + lr]);
    pk[k >> 1] = lo | (hi << 16);
  }
  ushort* dp = dst + ((size_t)b * L + l0 + lr) * R + r0 + rb;
  *(uint4*)dp = *(uint4*)pk;
  *(uint4*)(dp + 8) = *(uint4*)(pk + 4);
}

// ---------------------------------------------------------------------------
// Kernel 1 (MFMA): per (m-chunk of 256, h, b):
//   K^T = C_b^T @ Wk_h^T; P = exp(K); V^T likewise; ctx[d][e] = sum_m P V;
//   Z[d] = rowsum(P).
// Restructured for occupancy: each wave processes its 64 m rows as 2 halves
// of 32; K and V projections are SEPARATE passes (one 32-reg accumulator live
// at a time next to the persistent 64-reg cacc).  P/V half-tiles are 4 KB
// each -> LDS 33 KB (was 65 KB); __launch_bounds__(256,3) caps regs at 170.
// Staging swizzle: granule g (8 bf16) of row d stored at g ^ (d&3) -> stores
// hit every bank exactly 4x (b64 minimum), b128 reads 8x (minimum).
// Cross-wave reduce reuses the staging buffer in two 8 KB phases.
// ---------------------------------------------------------------------------
__global__ __launch_bounds__(256, 3) void kv_mfma_kernel(
    const ushort* __restrict__ ctxt_bf,   // [B][N][C] bf16
    const ushort* __restrict__ wk_bf,     // [HID][C]
    const ushort* __restrict__ wv_bf,
    float* __restrict__ ctx_part,         // [B*H][16][64*64]  ([e][d])
    float* __restrict__ z_part)           // [B*H][16][64]
{
  __shared__ __align__(16) ushort pv[4 * 4096];   // 32 KB: per wave P[64][32]+V[64][32]
  __shared__ float zred[4][64];
  const int mt = blockIdx.x, h = blockIdx.y, b = blockIdx.z;
  const int tid = threadIdx.x;
  const int w = tid >> 6, lane = tid & 63;
  const int col = lane & 15, quad = lane >> 4;

  const size_t m_base = (size_t)mt * 256 + w * 64;
  const ushort* cb  = ctxt_bf + ((size_t)b * N + m_base) * C;
  const ushort* wkp = wk_bf + (size_t)(h * 64) * C;
  const ushort* wvp = wv_bf + (size_t)(h * 64) * C;

  ushort* wp  = pv + w * 4096;          // P half-tile, 4 KB
  ushort* wvs = wp + 2048;              // V half-tile, 4 KB

  const f32x4 z4 = {0.f, 0.f, 0.f, 0.f};
  f32x4 cacc[4][4];
#pragma unroll
  for (int i = 0; i < 4; ++i)
#pragma unroll
    for (int j = 0; j < 4; ++j) cacc[i][j] = z4;
  float zl[4] = {0.f, 0.f, 0.f, 0.f};

  const int c3 = col & 3;
  const int sub = (quad & 1) << 2;
  const int gq = quad >> 1;

#pragma unroll
  for (int mh = 0; mh < 2; ++mh) {
    const ushort* cbh = cb + (size_t)(mh * 32) * C;

    // ---- V projection (32 m rows): vacc[i][j] = V[m][e] ----
    {
      f32x4 vacc[2][4];
#pragma unroll
      for (int i = 0; i < 2; ++i)
#pragma unroll
        for (int j = 0; j < 4; ++j) vacc[i][j] = z4;
#pragma unroll
      for (int kk = 0; kk < 8; ++kk) {
        const int ko = kk * 32 + quad * 8;
        bf16x8 a[2], bw[4];
#pragma unroll
        for (int i = 0; i < 2; ++i)
          a[i] = *(const bf16x8*)(cbh + (size_t)(i * 16 + col) * C + ko);
#pragma unroll
        for (int j = 0; j < 4; ++j)
          bw[j] = *(const bf16x8*)(wvp + (size_t)(j * 16 + col) * C + ko);
#pragma unroll
        for (int i = 0; i < 2; ++i)
#pragma unroll
          for (int j = 0; j < 4; ++j) vacc[i][j] = mfma16(a[i], bw[j], vacc[i][j]);
      }
#pragma unroll
      for (int i = 0; i < 2; ++i)
#pragma unroll
        for (int j = 0; j < 4; ++j) {
          const int d = j * 16 + col;
          const int off = d * 32 + ((((i << 1) + gq) ^ c3) << 3) + sub;
          const f32x4 v4 = vacc[i][j];
          ushort4 vk; vk.x = f2bf(v4[0]); vk.y = f2bf(v4[1]);
          vk.z = f2bf(v4[2]); vk.w = f2bf(v4[3]);
          *(ushort4*)(wvs + off) = vk;
        }
    }

    // ---- K projection (32 m rows) + exp + Z partial + stage P ----
    {
      f32x4 kacc[2][4];
#pragma unroll
      for (int i = 0; i < 2; ++i)
#pragma unroll
        for (int j = 0; j < 4; ++j) kacc[i][j] = z4;
#pragma unroll
      for (int kk = 0; kk < 8; ++kk) {
        const int ko = kk * 32 + quad * 8;
        bf16x8 a[2], bw[4];
#pragma unroll
        for (int i = 0; i < 2; ++i)
          a[i] = *(const bf16x8*)(cbh + (size_t)(i * 16 + col) * C + ko);
#pragma unroll
        for (int j = 0; j < 4; ++j)
          bw[j] = *(const bf16x8*)(wkp + (size_t)(j * 16 + col) * C + ko);
#pragma unroll
        for (int i = 0; i < 2; ++i)
#pragma unroll
          for (int j = 0; j < 4; ++j) kacc[i][j] = mfma16(a[i], bw[j], kacc[i][j]);
      }
#pragma unroll
      for (int i = 0; i < 2; ++i)
#pragma unroll
        for (int j = 0; j < 4; ++j) {
          const int d = j * 16 + col;
          const int off = d * 32 + ((((i << 1) + gq) ^ c3) << 3) + sub;
          const f32x4 k4 = kacc[i][j];
          const float e0 = __expf(k4[0]), e1 = __expf(k4[1]);
          const float e2 = __expf(k4[2]), e3 = __expf(k4[3]);
          zl[j] += (e0 + e1) + (e2 + e3);
          ushort4 pk; pk.x = f2bf(e0); pk.y = f2bf(e1);
          pk.z = f2bf(e2); pk.w = f2bf(e3);
          *(ushort4*)(wp + off) = pk;
        }
    }

    // ---- PV accumulate over this half's 32 m (one MFMA K-step) ----
    {
      const int rswz = (quad ^ c3) << 3;
      bf16x8 pa[4], vb[4];
#pragma unroll
      for (int i = 0; i < 4; ++i)
        pa[i] = *(const bf16x8*)(wp + (i * 16 + col) * 32 + rswz);
#pragma unroll
      for (int j = 0; j < 4; ++j)
        vb[j] = *(const bf16x8*)(wvs + (j * 16 + col) * 32 + rswz);
#pragma unroll
      for (int i = 0; i < 4; ++i)
#pragma unroll
        for (int j = 0; j < 4; ++j) cacc[i][j] = mfma16(pa[i], vb[j], cacc[i][j]);
    }
  }

  // ---- Z: reduce over quads, stash per-wave ----
#pragma unroll
  for (int j = 0; j < 4; ++j) {
    float s = zl[j];
    s += __shfl_xor(s, 16); s += __shfl_xor(s, 32);
    if (quad == 0) zred[w][j * 16 + col] = s;
  }

  // ---- cross-wave ctx reduce in two 8 KB phases (reuse staging buffer) ----
  const int bh = b * H + h;
  float* outp = ctx_part + ((size_t)bh * 16 + mt) * 4096;
  float* cred = (float*)(pv + (size_t)w * 4096);   // 2048 floats per wave
  const float* r0 = (const float*)pv;

#pragma unroll
  for (int ph = 0; ph < 2; ++ph) {
#pragma unroll
    for (int i = 0; i < 4; ++i)
#pragma unroll
      for (int j = 0; j < 2; ++j) {
        const int el = j * 16 + col;                     // local e in [0,32)
        const int off = el * 64 + (((i * 4 + quad) ^ col) << 2);
        *(f32x4*)(cred + off) = cacc[i][ph * 2 + j];
      }
    __syncthreads();
#pragma unroll
    for (int k = 0; k < 2; ++k) {
      const int g = tid + k * 256;                       // 512 f32x4 items
      const int el = g >> 4, dg = g & 15;
      const int off = el * 64 + ((dg ^ (el & 15)) << 2);
      f32x4 s = *(const f32x4*)(r0 + off);
      s += *(const f32x4*)(r0 + 2048 + off);
      s += *(const f32x4*)(r0 + 4096 + off);
      s += *(const f32x4*)(r0 + 6144 + off);
      *(f32x4*)(outp + (size_t)(ph * 32 + el) * 64 + dg * 4) = s;
    }
    if (ph == 0) __syncthreads();
  }
  if (tid < 64)
    z_part[((size_t)bh * 16 + mt) * 64 + tid] =
        (zred[0][tid] + zred[1][tid]) + (zred[2][tid] + zred[3][tid]);
}

// ---------------------------------------------------------------------------
// Kernel 2: sum partials, normalize cols by Z, fold in scale.  ctxn is [e][d].
// Grid (B*H, 16): 1024 blocks, 256 outputs each.
// ---------------------------------------------------------------------------
__global__ __launch_bounds__(256) void combine_kernel(
    const float* __restrict__ ctx_part, const float* __restrict__ z_part,
    float* __restrict__ ctxn)            // [B*H][64(e)][64(d)]
{
  const int bh = blockIdx.x, seg = blockIdx.y, tid = threadIdx.x;
  __shared__ float zs[64];
  if (tid < 64) {
    float z = 0.f;
#pragma unroll
    for (int p = 0; p < 16; ++p) z += z_part[((size_t)bh * 16 + p) * 64 + tid];
    zs[tid] = SCALE / z;
  }
  __syncthreads();
  const int idx = (seg << 8) + tid;
  const float* cp = ctx_part + (size_t)bh * 16 * 4096;
  float s = 0.f;
#pragma unroll
  for (int p = 0; p < 16; ++p) s += cp[(size_t)p * 4096 + idx];
  ctxn[((size_t)bh << 12) + idx] = s * zs[idx & 63];
}

// ---------------------------------------------------------------------------
// Kernel 3a: A[b][h*64+e][c] = sum_d ctxn[b,h][e][d] * Wq[h*64+d, c]   (fp32)
// Grid (B*H, 4): one 64-col c-tile per block.
// ---------------------------------------------------------------------------
__global__ __launch_bounds__(256) void a_kernel(
    const float* __restrict__ ctxn, const float* __restrict__ Wq,
    float* __restrict__ A)               // [B][HID][C]
{
  const int bh = blockIdx.x, cti = blockIdx.y, tid = threadIdx.x;
  const int b = bh >> 3, h = bh & 7;
  const int c0 = cti << 6;
  __shared__ float ct[64 * 65];   // [e][d]
  __shared__ float wq[64 * 68];   // [d][c-tile]
  for (int r = 0; r < 16; ++r) {
    const int idx = tid + (r << 8);
    ct[(idx >> 6) * 65 + (idx & 63)] = ctxn[((size_t)bh << 12) + idx];
    wq[(idx >> 6) * 68 + (idx & 63)] =
        Wq[(size_t)(h * 64 + (idx >> 6)) * C + c0 + (idx & 63)];
  }
  __syncthreads();
  const int e = tid & 63, co = tid >> 6;
  float acc[16];
#pragma unroll
  for (int k = 0; k < 16; ++k) acc[k] = 0.f;
  for (int d = 0; d < 64; ++d) {
    const float cv = ct[e * 65 + d];
    const float* wr = wq + d * 68 + co * 16;
#pragma unroll
    for (int k = 0; k < 16; ++k) acc[k] += cv * wr[k];
  }
  float* Ar = A + ((size_t)b * HID + h * 64 + e) * C + c0 + co * 16;
#pragma unroll
  for (int k = 0; k < 16; ++k) Ar[k] = acc[k];
}

// ---------------------------------------------------------------------------
// Kernel 3b: M[b] = Wo (256x512) @ A[b] (512x256)  -> bf16 [b][o][c]
// 32x64 tiles, grid (32, B) = 256 blocks.
// ---------------------------------------------------------------------------
__global__ __launch_bounds__(256) void m_kernel(
    const float* __restrict__ A, const float* __restrict__ Wo,
    ushort* __restrict__ M_bf)
{
  const int tile = blockIdx.x, b = blockIdx.y;
  const int o0 = (tile & 7) << 5, c0 = (tile >> 3) << 6;
  const int tid = threadIdx.x, tx = tid & 15, ty = tid >> 4;
  __shared__ float wo_s[16 * 36];  // [k][o 32]
  __shared__ float a_s[16 * 68];   // [k][c 64]
  float acc[2][4] = {{0.f}};
  const int ow = tid >> 3, koff = (tid & 7) << 1;
  const int kk = tid >> 4, cc = (tid & 15) << 2;
  for (int k0 = 0; k0 < HID; k0 += 16) {
    __syncthreads();
    const float2 w2 = *(const float2*)(Wo + (size_t)(o0 + ow) * HID + k0 + koff);
    wo_s[(koff + 0) * 36 + ow] = w2.x;
    wo_s[(koff + 1) * 36 + ow] = w2.y;
    *(float4*)(a_s + kk * 68 + cc) =
        *(const float4*)(A + ((size_t)b * HID + k0 + kk) * C + c0 + cc);
    __syncthreads();
#pragma unroll
    for (int kc = 0; kc < 16; ++kc) {
      const float2 wv = *(const float2*)(wo_s + kc * 36 + ty * 2);
      const float4 av = *(const float4*)(a_s + kc * 68 + tx * 4);
      acc[0][0] += wv.x * av.x; acc[0][1] += wv.x * av.y;
      acc[0][2] += wv.x * av.z; acc[0][3] += wv.x * av.w;
      acc[1][0] += wv.y * av.x; acc[1][1] += wv.y * av.y;
      acc[1][2] += wv.y * av.z; acc[1][3] += wv.y * av.w;
    }
  }
#pragma unroll
  for (int i = 0; i < 2; ++i) {
    ushort4 r;
    r.x = f2bf(acc[i][0]); r.y = f2bf(acc[i][1]);
    r.z = f2bf(acc[i][2]); r.w = f2bf(acc[i][3]);
    *(ushort4*)(M_bf + ((size_t)b * C + o0 + ty * 2 + i) * C + c0 + tx * 4) = r;
  }
}

// ---------------------------------------------------------------------------
// Kernel 4 (MFMA): out[b] = M_b (256x256) @ X_b (256x4096) + bo
// o-tile 32 -> grid (16, 8, 8) = 1024 blocks, acc[2][4] = 32 regs/thread.
// ---------------------------------------------------------------------------
__global__ __launch_bounds__(256, 4) void out_mfma_kernel(
    const ushort* __restrict__ M_bf,     // [B][C][C] bf16
    const ushort* __restrict__ x_bf,     // [B][N][C] bf16
    const float* __restrict__ bo, float* __restrict__ out)
{
  const int nt = blockIdx.x, ot = blockIdx.y, b = blockIdx.z;
  const int tid = threadIdx.x;
  const int w = tid >> 6, lane = tid & 63;
  const int col = lane & 15, quad = lane >> 4;
  const int o0 = ot * 32;
  const size_t n_base = (size_t)nt * 256 + w * 64;
  const ushort* Ab = M_bf + ((size_t)b * C + o0 + col) * C + quad * 8;
  const ushort* Bb = x_bf + ((size_t)b * N + n_base) * C + quad * 8;

  const f32x4 z4 = {0.f, 0.f, 0.f, 0.f};
  f32x4 acc[2][4];
#pragma unroll
  for (int i = 0; i < 2; ++i)
#pragma unroll
    for (int j = 0; j < 4; ++j) acc[i][j] = z4;

#pragma unroll
  for (int kk = 0; kk < 8; ++kk) {
    bf16x8 af[2], bfz[4];
#pragma unroll
    for (int i = 0; i < 2; ++i)
      af[i] = *(const bf16x8*)(Ab + (size_t)(i * 16) * C + kk * 32);
#pragma unroll
    for (int j = 0; j < 4; ++j)
      bfz[j] = *(const bf16x8*)(Bb + (size_t)(j * 16 + col) * C + kk * 32);
#pragma unroll
    for (int i = 0; i < 2; ++i)
#pragma unroll
      for (int j = 0; j < 4; ++j) acc[i][j] = mfma16(af[i], bfz[j], acc[i][j]);
  }

#pragma unroll
  for (int i = 0; i < 2; ++i)
#pragma unroll
    for (int r = 0; r < 4; ++r) {
      const int o = o0 + i * 16 + quad * 4 + r;
      const float bias = bo[o];
      float* op = out + ((size_t)b * C + o) * N + n_base + col;
#pragma unroll
      for (int j = 0; j < 4; ++j) op[j * 16] = acc[i][j][r] + bias;
    }
}

// ---------------------------------------------------------------------------
extern "C" void kernel_launch(void* const* d_in, const int* in_sizes, int n_in,
                              void* d_out, int out_size, void* d_ws, size_t ws_size,
                              hipStream_t stream) {
  const float* x    = (const float*)d_in[0];
  const float* ctxt = (const float*)d_in[1];
  const float* Wq   = (const float*)d_in[2];
  const float* Wk   = (const float*)d_in[3];
  const float* Wv   = (const float*)d_in[4];
  const float* Wo   = (const float*)d_in[5];
  const float* bo   = (const float*)d_in[6];
  float* out = (float*)d_out;

  char* p = (char*)d_ws;
  ushort* ctxt_bf = (ushort*)p;  p += (size_t)B * N * C * 2;        // 16 MB (x_bf aliases)
  ushort* wk_bf   = (ushort*)p;  p += (size_t)HID * C * 2;
  ushort* wv_bf   = (ushort*)p;  p += (size_t)HID * C * 2;
  ushort* M_bf    = (ushort*)p;  p += (size_t)B * C * C * 2;
  float*  z_part  = (float*)p;   p += (size_t)B * H * 16 * 64 * 4;
  float*  ctxn    = (float*)p;   p += (size_t)B * H * D * D * 4;
  float*  ctx_part= (float*)p;   p += (size_t)B * H * 16 * 4096 * 4; // 16.8 MB
  float*  A       = ctx_part;    // aliased: ctx_part dead after combine_kernel
  ushort* x_bf    = ctxt_bf;     // reused after kv_mfma_kernel

  cast_w_kernel<<<dim3(HID * C / 1024), 256, 0, stream>>>(Wk, Wv, wk_bf, wv_bf);
  transpose_cast_kernel<<<dim3(N / 64, C / 64, B), 256, 0, stream>>>(ctxt, ctxt_bf, C, N);
  kv_mfma_kernel<<<dim3(16, H, B), 256, 0, stream>>>(ctxt_bf, wk_bf, wv_bf, ctx_part, z_part);
  transpose_cast_kernel<<<dim3(N / 64, C / 64, B), 256, 0, stream>>>(x, x_bf, C, N);
  combine_kernel<<<dim3(B * H, 16), 256, 0, stream>>>(ctx_part, z_part, ctxn);
  a_kernel<<<dim3(B * H, 4), 256, 0, stream>>>(ctxn, Wq, A);
  m_kernel<<<dim3(32, B), 256, 0, stream>>>(A, Wo, M_bf);
  out_mfma_kernel<<<dim3(N / 256, C / 32, B), 256, 0, stream>>>(M_bf, x_bf, bo, out);
}

// Round 2
// 219.442 us; speedup vs baseline: 1.3585x; 1.3585x over previous
//
#include <hip/hip_runtime.h>

#define B   8
#define C   256
#define N   4096
#define H   8
#define D   64
#define HID 512
#define SCALE 0.125f

typedef __attribute__((ext_vector_type(8))) __bf16 bf16x8;
typedef __attribute__((ext_vector_type(4))) float f32x4;

__device__ __forceinline__ ushort f2bf(float f) {
  union { float f; unsigned u; } v; v.f = f;
  unsigned r = v.u + 0x7FFFu + ((v.u >> 16) & 1u);
  return (ushort)(r >> 16);
}

__device__ __forceinline__ f32x4 mfma16(bf16x8 a, bf16x8 b, f32x4 c) {
  return __builtin_amdgcn_mfma_f32_16x16x32_bf16(a, b, c, 0, 0, 0);
}

// ---------------------------------------------------------------------------
// Cast Wk, Wv to bf16 (row-major [HID][C] kept).
// ---------------------------------------------------------------------------
__global__ __launch_bounds__(256) void cast_w_kernel(
    const float* __restrict__ Wk, const float* __restrict__ Wv,
    ushort* __restrict__ wk_bf, ushort* __restrict__ wv_bf) {
  const int t = (blockIdx.x * 256 + threadIdx.x) * 4;   // HID*C = 131072 elems
  const float4 a = *(const float4*)(Wk + t);
  const float4 b = *(const float4*)(Wv + t);
  ushort4 ra, rb;
  ra.x = f2bf(a.x); ra.y = f2bf(a.y); ra.z = f2bf(a.z); ra.w = f2bf(a.w);
  rb.x = f2bf(b.x); rb.y = f2bf(b.y); rb.z = f2bf(b.z); rb.w = f2bf(b.w);
  *(ushort4*)(wk_bf + t) = ra;
  *(ushort4*)(wv_bf + t) = rb;
}

// ---------------------------------------------------------------------------
// Transpose+cast: src fp32 [b][R][L] -> dst bf16 [b][L][R].  64x64 tiles.
// ---------------------------------------------------------------------------
__global__ __launch_bounds__(256) void transpose_cast_kernel(
    const float* __restrict__ src, ushort* __restrict__ dst, int R, int L) {
  __shared__ float tile[64 * 65];
  const int l0 = blockIdx.x * 64, r0 = blockIdx.y * 64, b = blockIdx.z;
  const int tid = threadIdx.x;
  const int rr = tid >> 4, c4 = (tid & 15) << 2;
  const float* sp = src + ((size_t)b * R + r0) * L + l0;
#pragma unroll
  for (int p = 0; p < 4; ++p) {
    const float4 v = *(const float4*)(sp + (size_t)(rr + p * 16) * L + c4);
    float* tp = tile + (rr + p * 16) * 65 + c4;
    tp[0] = v.x; tp[1] = v.y; tp[2] = v.z; tp[3] = v.w;
  }
  __syncthreads();
  const int lr = tid >> 2, rb = (tid & 3) << 4;
  uint pk[8];
#pragma unroll
  for (int k = 0; k < 16; k += 2) {
    const uint lo = f2bf(tile[(rb + k) * 65 + lr]);
    const uint hi = f2bf(tile[(rb + k + 1) * 65 + lr]);
    pk[k >> 1] = lo | (hi << 16);
  }
  ushort* dp = dst + ((size_t)b * L + l0 + lr) * R + r0 + rb;
  *(uint4*)dp = *(uint4*)pk;
  *(uint4*)(dp + 8) = *(uint4*)(pk + 4);
}

// ---------------------------------------------------------------------------
// Kernel 1 (MFMA), wave-per-d-slice decomposition:
//   Block = (m-tile of 256, h, b), 4 waves.  Wave w owns d/e slice
//   [w*16, w*16+16).  Per 64-m sub-tile: stage ctxt[64][256] into LDS
//   (XOR-granule swizzle, conflict-free), project K,V for own slice
//   (kacc[4]+vacc[4]=32 regs), exp+stage P/V [64 rows][64 m] bf16 in LDS,
//   PV-accumulate into cacc[4] (16 regs).  No cross-wave ctx reduction:
//   each wave owns its 16 ctx d-rows.  2 barriers per sub-tile.
//   ctx_part layout is [d][e] (coalesced epilogue store).
// ---------------------------------------------------------------------------
__global__ __launch_bounds__(256, 3) void kv_mfma_kernel(
    const ushort* __restrict__ ctxt_bf,   // [B][N][C] bf16
    const ushort* __restrict__ wk_bf,     // [HID][C]
    const ushort* __restrict__ wv_bf,
    float* __restrict__ ctx_part,         // [B*H][16][64*64]  ([d][e])
    float* __restrict__ z_part)           // [B*H][16][64]
{
  __shared__ __align__(16) ushort cb_s[64 * 256];   // 32 KB ctxt sub-tile
  __shared__ __align__(16) ushort p_s[64 * 64];     // 8 KB  P (bf16, [d][m])
  __shared__ __align__(16) ushort v_s[64 * 64];     // 8 KB  V (bf16, [e][m])
  const int mt = blockIdx.x, h = blockIdx.y, b = blockIdx.z;
  const int tid = threadIdx.x;
  const int w = tid >> 6, lane = tid & 63;
  const int col = lane & 15, quad = lane >> 4;
  const int dw = w * 16;                  // wave's d/e slice base
  const int c7 = col & 7;

  const ushort* wkp = wk_bf + (size_t)(h * 64 + dw + col) * C + quad * 8;
  const ushort* wvp = wv_bf + (size_t)(h * 64 + dw + col) * C + quad * 8;

  const int sgcol = lane & 31;            // stage granule col
  const int srowo = w * 16 + (lane >> 5); // stage row base (+ it*2)

  const f32x4 z4 = {0.f, 0.f, 0.f, 0.f};
  f32x4 cacc[4];
#pragma unroll
  for (int j = 0; j < 4; ++j) cacc[j] = z4;
  float zl = 0.f;

  for (int mh = 0; mh < 4; ++mh) {
    const size_t m0 = (size_t)mt * 256 + mh * 64;
    const ushort* cbg = ctxt_bf + ((size_t)b * N + m0) * C;

    // ---- stage ctxt 64x256 -> LDS with XOR granule swizzle ----
#pragma unroll
    for (int it = 0; it < 8; ++it) {
      const int row = srowo + it * 2;
      const uint4 vld = *(const uint4*)(cbg + (size_t)row * C + sgcol * 8);
      const int gc = sgcol ^ (row & 7);
      *(uint4*)(cb_s + row * 256 + gc * 8) = vld;
    }
    __syncthreads();

    // ---- K+V projection for own d-slice (weights in 4-kk chunks) ----
    f32x4 kacc[4], vacc[4];
#pragma unroll
    for (int i = 0; i < 4; ++i) { kacc[i] = z4; vacc[i] = z4; }
#pragma unroll
    for (int kc = 0; kc < 2; ++kc) {
      bf16x8 wkf[4], wvf[4];
#pragma unroll
      for (int kk = 0; kk < 4; ++kk) {
        wkf[kk] = *(const bf16x8*)(wkp + (size_t)(kc * 4 + kk) * 32);
        wvf[kk] = *(const bf16x8*)(wvp + (size_t)(kc * 4 + kk) * 32);
      }
#pragma unroll
      for (int kk = 0; kk < 4; ++kk) {
        const int kg = (kc * 4 + kk) * 4 + quad;   // K granule 0..31
        bf16x8 a[4];
#pragma unroll
        for (int i = 0; i < 4; ++i) {
          const int r = i * 16 + col;
          a[i] = *(const bf16x8*)(cb_s + r * 256 + (kg ^ (r & 7)) * 8);
        }
#pragma unroll
        for (int i = 0; i < 4; ++i) {
          kacc[i] = mfma16(a[i], wkf[kk], kacc[i]);
          vacc[i] = mfma16(a[i], wvf[kk], vacc[i]);
        }
      }
    }

    // ---- exp + stage P/V (own 16 rows), Z partial ----
#pragma unroll
    for (int i = 0; i < 4; ++i) {
      const int off = (dw + col) * 64 + (((i * 2 + (quad >> 1)) ^ c7) << 3) +
                      ((quad & 1) << 2);
      const f32x4 k4 = kacc[i];
      const float e0 = __expf(k4[0]), e1 = __expf(k4[1]);
      const float e2 = __expf(k4[2]), e3 = __expf(k4[3]);
      zl += (e0 + e1) + (e2 + e3);
      ushort4 pk; pk.x = f2bf(e0); pk.y = f2bf(e1);
      pk.z = f2bf(e2); pk.w = f2bf(e3);
      *(ushort4*)(p_s + off) = pk;
      const f32x4 v4 = vacc[i];
      ushort4 vk; vk.x = f2bf(v4[0]); vk.y = f2bf(v4[1]);
      vk.z = f2bf(v4[2]); vk.w = f2bf(v4[3]);
      *(ushort4*)(v_s + off) = vk;
    }
    __syncthreads();

    // ---- PV accumulate: ctx[own d 16][e 64] over 64 m (2 K-steps) ----
#pragma unroll
    for (int kq = 0; kq < 2; ++kq) {
      const int gsw = ((kq * 4 + quad) ^ c7) << 3;
      const bf16x8 pa = *(const bf16x8*)(p_s + (dw + col) * 64 + gsw);
      bf16x8 vb[4];
#pragma unroll
      for (int j = 0; j < 4; ++j)
        vb[j] = *(const bf16x8*)(v_s + (j * 16 + col) * 64 + gsw);
#pragma unroll
      for (int j = 0; j < 4; ++j) cacc[j] = mfma16(pa, vb[j], cacc[j]);
    }
    // next stage writes cb_s only (disjoint from p_s/v_s) -> no barrier here;
    // p_s/v_s rewritten only after the next sub-tile's post-stage barrier.
  }

  // ---- Z: reduce over quads (lanes sharing col = same d) ----
  {
    float s = zl;
    s += __shfl_xor(s, 16); s += __shfl_xor(s, 32);
    if (quad == 0)
      z_part[((size_t)(b * H + h) * 16 + mt) * 64 + dw + col] = s;
  }

  // ---- ctx epilogue: [d][e], coalesced 64B segments ----
  float* outp = ctx_part + ((size_t)(b * H + h) * 16 + mt) * 4096;
#pragma unroll
  for (int j = 0; j < 4; ++j)
#pragma unroll
    for (int r = 0; r < 4; ++r)
      outp[(size_t)(dw + quad * 4 + r) * 64 + j * 16 + col] = cacc[j][r];
}

// ---------------------------------------------------------------------------
// Kernel 2: sum partials, normalize by Z (per d = idx>>6), fold in scale.
// ctx_part / ctxn are [d][e].  Grid (B*H, 16).
// ---------------------------------------------------------------------------
__global__ __launch_bounds__(256) void combine_kernel(
    const float* __restrict__ ctx_part, const float* __restrict__ z_part,
    float* __restrict__ ctxn)            // [B*H][64(d)][64(e)]
{
  const int bh = blockIdx.x, seg = blockIdx.y, tid = threadIdx.x;
  __shared__ float zs[64];
  if (tid < 64) {
    float z = 0.f;
#pragma unroll
    for (int p = 0; p < 16; ++p) z += z_part[((size_t)bh * 16 + p) * 64 + tid];
    zs[tid] = SCALE / z;
  }
  __syncthreads();
  const int idx = (seg << 8) + tid;
  const float* cp = ctx_part + (size_t)bh * 16 * 4096;
  float s = 0.f;
#pragma unroll
  for (int p = 0; p < 16; ++p) s += cp[(size_t)p * 4096 + idx];
  ctxn[((size_t)bh << 12) + idx] = s * zs[idx >> 6];
}

// ---------------------------------------------------------------------------
// Kernel 3a: A[b][h*64+e][c] = sum_d ctxn[b,h][d][e] * Wq[h*64+d, c]   (fp32)
// Grid (B*H, 4): one 64-col c-tile per block.  ctxn is [d][e] -> transpose
// into ct[e][d] on LDS fill.
// ---------------------------------------------------------------------------
__global__ __launch_bounds__(256) void a_kernel(
    const float* __restrict__ ctxn, const float* __restrict__ Wq,
    float* __restrict__ A)               // [B][HID][C]
{
  const int bh = blockIdx.x, cti = blockIdx.y, tid = threadIdx.x;
  const int b = bh >> 3, h = bh & 7;
  const int c0 = cti << 6;
  __shared__ float ct[64 * 65];   // [e][d]
  __shared__ float wq[64 * 68];   // [d][c-tile]
  for (int r = 0; r < 16; ++r) {
    const int idx = tid + (r << 8);
    ct[(idx & 63) * 65 + (idx >> 6)] = ctxn[((size_t)bh << 12) + idx];
    wq[(idx >> 6) * 68 + (idx & 63)] =
        Wq[(size_t)(h * 64 + (idx >> 6)) * C + c0 + (idx & 63)];
  }
  __syncthreads();
  const int e = tid & 63, co = tid >> 6;
  float acc[16];
#pragma unroll
  for (int k = 0; k < 16; ++k) acc[k] = 0.f;
  for (int d = 0; d < 64; ++d) {
    const float cv = ct[e * 65 + d];
    const float* wr = wq + d * 68 + co * 16;
#pragma unroll
    for (int k = 0; k < 16; ++k) acc[k] += cv * wr[k];
  }
  float* Ar = A + ((size_t)b * HID + h * 64 + e) * C + c0 + co * 16;
#pragma unroll
  for (int k = 0; k < 16; ++k) Ar[k] = acc[k];
}

// ---------------------------------------------------------------------------
// Kernel 3b: M[b] = Wo (256x512) @ A[b] (512x256)  -> bf16 [b][o][c]
// 32x64 tiles, grid (32, B) = 256 blocks.
// ---------------------------------------------------------------------------
__global__ __launch_bounds__(256) void m_kernel(
    const float* __restrict__ A, const float* __restrict__ Wo,
    ushort* __restrict__ M_bf)
{
  const int tile = blockIdx.x, b = blockIdx.y;
  const int o0 = (tile & 7) << 5, c0 = (tile >> 3) << 6;
  const int tid = threadIdx.x, tx = tid & 15, ty = tid >> 4;
  __shared__ float wo_s[16 * 36];  // [k][o 32]
  __shared__ float a_s[16 * 68];   // [k][c 64]
  float acc[2][4] = {{0.f}};
  const int ow = tid >> 3, koff = (tid & 7) << 1;
  const int kk = tid >> 4, cc = (tid & 15) << 2;
  for (int k0 = 0; k0 < HID; k0 += 16) {
    __syncthreads();
    const float2 w2 = *(const float2*)(Wo + (size_t)(o0 + ow) * HID + k0 + koff);
    wo_s[(koff + 0) * 36 + ow] = w2.x;
    wo_s[(koff + 1) * 36 + ow] = w2.y;
    *(float4*)(a_s + kk * 68 + cc) =
        *(const float4*)(A + ((size_t)b * HID + k0 + kk) * C + c0 + cc);
    __syncthreads();
#pragma unroll
    for (int kc = 0; kc < 16; ++kc) {
      const float2 wv = *(const float2*)(wo_s + kc * 36 + ty * 2);
      const float4 av = *(const float4*)(a_s + kc * 68 + tx * 4);
      acc[0][0] += wv.x * av.x; acc[0][1] += wv.x * av.y;
      acc[0][2] += wv.x * av.z; acc[0][3] += wv.x * av.w;
      acc[1][0] += wv.y * av.x; acc[1][1] += wv.y * av.y;
      acc[1][2] += wv.y * av.z; acc[1][3] += wv.y * av.w;
    }
  }
#pragma unroll
  for (int i = 0; i < 2; ++i) {
    ushort4 r;
    r.x = f2bf(acc[i][0]); r.y = f2bf(acc[i][1]);
    r.z = f2bf(acc[i][2]); r.w = f2bf(acc[i][3]);
    *(ushort4*)(M_bf + ((size_t)b * C + o0 + ty * 2 + i) * C + c0 + tx * 4) = r;
  }
}

// ---------------------------------------------------------------------------
// Kernel 4 (MFMA): out[b] = M_b (256x256) @ X_b (256x4096) + bo
// o-tile 32 -> grid (16, 8, 8) = 1024 blocks, acc[2][4] = 32 regs/thread.
// ---------------------------------------------------------------------------
__global__ __launch_bounds__(256, 4) void out_mfma_kernel(
    const ushort* __restrict__ M_bf,     // [B][C][C] bf16
    const ushort* __restrict__ x_bf,     // [B][N][C] bf16
    const float* __restrict__ bo, float* __restrict__ out)
{
  const int nt = blockIdx.x, ot = blockIdx.y, b = blockIdx.z;
  const int tid = threadIdx.x;
  const int w = tid >> 6, lane = tid & 63;
  const int col = lane & 15, quad = lane >> 4;
  const int o0 = ot * 32;
  const size_t n_base = (size_t)nt * 256 + w * 64;
  const ushort* Ab = M_bf + ((size_t)b * C + o0 + col) * C + quad * 8;
  const ushort* Bb = x_bf + ((size_t)b * N + n_base) * C + quad * 8;

  const f32x4 z4 = {0.f, 0.f, 0.f, 0.f};
  f32x4 acc[2][4];
#pragma unroll
  for (int i = 0; i < 2; ++i)
#pragma unroll
    for (int j = 0; j < 4; ++j) acc[i][j] = z4;

#pragma unroll
  for (int kk = 0; kk < 8; ++kk) {
    bf16x8 af[2], bfz[4];
#pragma unroll
    for (int i = 0; i < 2; ++i)
      af[i] = *(const bf16x8*)(Ab + (size_t)(i * 16) * C + kk * 32);
#pragma unroll
    for (int j = 0; j < 4; ++j)
      bfz[j] = *(const bf16x8*)(Bb + (size_t)(j * 16 + col) * C + kk * 32);
#pragma unroll
    for (int i = 0; i < 2; ++i)
#pragma unroll
      for (int j = 0; j < 4; ++j) acc[i][j] = mfma16(af[i], bfz[j], acc[i][j]);
  }

#pragma unroll
  for (int i = 0; i < 2; ++i)
#pragma unroll
    for (int r = 0; r < 4; ++r) {
      const int o = o0 + i * 16 + quad * 4 + r;
      const float bias = bo[o];
      float* op = out + ((size_t)b * C + o) * N + n_base + col;
#pragma unroll
      for (int j = 0; j < 4; ++j) op[j * 16] = acc[i][j][r] + bias;
    }
}

// ---------------------------------------------------------------------------
extern "C" void kernel_launch(void* const* d_in, const int* in_sizes, int n_in,
                              void* d_out, int out_size, void* d_ws, size_t ws_size,
                              hipStream_t stream) {
  const float* x    = (const float*)d_in[0];
  const float* ctxt = (const float*)d_in[1];
  const float* Wq   = (const float*)d_in[2];
  const float* Wk   = (const float*)d_in[3];
  const float* Wv   = (const float*)d_in[4];
  const float* Wo   = (const float*)d_in[5];
  const float* bo   = (const float*)d_in[6];
  float* out = (float*)d_out;

  char* p = (char*)d_ws;
  ushort* ctxt_bf = (ushort*)p;  p += (size_t)B * N * C * 2;        // 16 MB (x_bf aliases)
  ushort* wk_bf   = (ushort*)p;  p += (size_t)HID * C * 2;
  ushort* wv_bf   = (ushort*)p;  p += (size_t)HID * C * 2;
  ushort* M_bf    = (ushort*)p;  p += (size_t)B * C * C * 2;
  float*  z_part  = (float*)p;   p += (size_t)B * H * 16 * 64 * 4;
  float*  ctxn    = (float*)p;   p += (size_t)B * H * D * D * 4;
  float*  ctx_part= (float*)p;   p += (size_t)B * H * 16 * 4096 * 4; // 16.8 MB
  float*  A       = ctx_part;    // aliased: ctx_part dead after combine_kernel
  ushort* x_bf    = ctxt_bf;     // reused after kv_mfma_kernel

  cast_w_kernel<<<dim3(HID * C / 1024), 256, 0, stream>>>(Wk, Wv, wk_bf, wv_bf);
  transpose_cast_kernel<<<dim3(N / 64, C / 64, B), 256, 0, stream>>>(ctxt, ctxt_bf, C, N);
  kv_mfma_kernel<<<dim3(16, H, B), 256, 0, stream>>>(ctxt_bf, wk_bf, wv_bf, ctx_part, z_part);
  transpose_cast_kernel<<<dim3(N / 64, C / 64, B), 256, 0, stream>>>(x, x_bf, C, N);
  combine_kernel<<<dim3(B * H, 16), 256, 0, stream>>>(ctx_part, z_part, ctxn);
  a_kernel<<<dim3(B * H, 4), 256, 0, stream>>>(ctxn, Wq, A);
  m_kernel<<<dim3(32, B), 256, 0, stream>>>(A, Wo, M_bf);
  out_mfma_kernel<<<dim3(N / 256, C / 32, B), 256, 0, stream>>>(M_bf, x_bf, bo, out);
}

// Round 3
// 217.968 us; speedup vs baseline: 1.3677x; 1.0068x over previous
//
#include <hip/hip_runtime.h>

#define B   8
#define C   256
#define N   4096
#define H   8
#define D   64
#define HID 512
#define SCALE 0.125f

typedef __attribute__((ext_vector_type(8))) __bf16 bf16x8;
typedef __attribute__((ext_vector_type(4))) float f32x4;

__device__ __forceinline__ ushort f2bf(float f) {
  union { float f; unsigned u; } v; v.f = f;
  unsigned r = v.u + 0x7FFFu + ((v.u >> 16) & 1u);
  return (ushort)(r >> 16);
}

__device__ __forceinline__ f32x4 mfma16(bf16x8 a, bf16x8 b, f32x4 c) {
  return __builtin_amdgcn_mfma_f32_16x16x32_bf16(a, b, c, 0, 0, 0);
}

// global -> LDS direct DMA, 16 B per lane.  LDS dest must be wave-uniform
// base (HW adds lane*16); global src is per-lane (pre-swizzled there).
__device__ __forceinline__ void glds16(const ushort* g, ushort* l) {
  __builtin_amdgcn_global_load_lds(
      (const __attribute__((address_space(1))) void*)g,
      (__attribute__((address_space(3))) void*)l, 16, 0, 0);
}

// ---------------------------------------------------------------------------
// Fused prep: z<8  -> transpose+cast ctxt[b] (fp32 [C][N] -> bf16 [N][C])
//             z<16 -> transpose+cast x[b-8]
//             z=16 -> cast Wk/Wv to bf16 (first 128 blocks of the plane)
// ---------------------------------------------------------------------------
__global__ __launch_bounds__(256) void prep_kernel(
    const float* __restrict__ x, const float* __restrict__ ctxt,
    const float* __restrict__ Wk, const float* __restrict__ Wv,
    ushort* __restrict__ x_bf, ushort* __restrict__ ctxt_bf,
    ushort* __restrict__ wk_bf, ushort* __restrict__ wv_bf) {
  const int z = blockIdx.z;
  if (z == 16) {
    const int id = blockIdx.y * 64 + blockIdx.x;
    if (id >= 128) return;
    const int t = (id * 256 + threadIdx.x) * 4;   // HID*C = 131072 elems
    const float4 a = *(const float4*)(Wk + t);
    const float4 b = *(const float4*)(Wv + t);
    ushort4 ra, rb;
    ra.x = f2bf(a.x); ra.y = f2bf(a.y); ra.z = f2bf(a.z); ra.w = f2bf(a.w);
    rb.x = f2bf(b.x); rb.y = f2bf(b.y); rb.z = f2bf(b.z); rb.w = f2bf(b.w);
    *(ushort4*)(wk_bf + t) = ra;
    *(ushort4*)(wv_bf + t) = rb;
    return;
  }
  __shared__ float tile[64 * 65];
  const int b = z & 7;
  const float* src = (z < 8) ? ctxt : x;
  ushort* dst = (z < 8) ? ctxt_bf : x_bf;
  const int l0 = blockIdx.x * 64, r0 = blockIdx.y * 64;
  const int tid = threadIdx.x;
  const int rr = tid >> 4, c4 = (tid & 15) << 2;
  const float* sp = src + ((size_t)b * C + r0) * N + l0;
#pragma unroll
  for (int p = 0; p < 4; ++p) {
    const float4 v = *(const float4*)(sp + (size_t)(rr + p * 16) * N + c4);
    float* tp = tile + (rr + p * 16) * 65 + c4;
    tp[0] = v.x; tp[1] = v.y; tp[2] = v.z; tp[3] = v.w;
  }
  __syncthreads();
  const int lr = tid >> 2, rb = (tid & 3) << 4;
  uint pk[8];
#pragma unroll
  for (int k = 0; k < 16; k += 2) {
    const uint lo = f2bf(tile[(rb + k) * 65 + lr]);
    const uint hi = f2bf(tile[(rb + k + 1) * 65 + lr]);
    pk[k >> 1] = lo | (hi << 16);
  }
  ushort* dp = dst + ((size_t)b * N + l0 + lr) * C + r0 + rb;
  *(uint4*)dp = *(uint4*)pk;
  *(uint4*)(dp + 8) = *(uint4*)(pk + 4);
}

// ---------------------------------------------------------------------------
// Kernel 1 (MFMA), wave-per-d-slice + 32-m sub-tiles + glds double buffer:
//   Block = (m-tile 256, h, b), 4 waves; wave w owns d/e slice [16w,16w+16).
//   Per 32-m sub-tile t: prefetch tile t+1 via global_load_lds (pre-swizzled
//   global src, linear LDS dest), project K,V for own slice from cb_s[t&1],
//   exp+stage P/V bf16, one PV K-step into cacc[4].  2 barriers per sub-tile;
//   prefetch is in flight across the MFMA phase.  LDS 40 KB -> 4 blocks/CU.
// ---------------------------------------------------------------------------
__global__ __launch_bounds__(256, 4) void kv_mfma_kernel(
    const ushort* __restrict__ ctxt_bf,   // [B][N][C] bf16
    const ushort* __restrict__ wk_bf,     // [HID][C]
    const ushort* __restrict__ wv_bf,
    float* __restrict__ ctx_part,         // [B*H][16][64*64]  ([d][e])
    float* __restrict__ z_part)           // [B*H][16][64]
{
  __shared__ __align__(16) ushort cb_s[2][32 * 256];  // 2 x 16 KB ctxt tiles
  __shared__ __align__(16) ushort p_s[64 * 32];       // 4 KB P ([d][m32])
  __shared__ __align__(16) ushort v_s[64 * 32];       // 4 KB V ([e][m32])
  const int mt = blockIdx.x, h = blockIdx.y, b = blockIdx.z;
  const int tid = threadIdx.x;
  const int w = tid >> 6, lane = tid & 63;
  const int col = lane & 15, quad = lane >> 4;
  const int dw = w * 16;
  const int swc = (col & 3) ^ ((col >> 2) & 3);   // P/V granule swizzle

  const ushort* wkp = wk_bf + (size_t)(h * 64 + dw + col) * C + quad * 8;
  const ushort* wvp = wv_bf + (size_t)(h * 64 + dw + col) * C + quad * 8;
  const ushort* cbase = ctxt_bf + ((size_t)b * N + (size_t)mt * 256) * C;

  const int grow0 = w * 8 + (lane >> 5);   // staging row (+ it*2)
  const int ggran = lane & 31;             // staging granule (16 B)

  const f32x4 z4 = {0.f, 0.f, 0.f, 0.f};
  f32x4 cacc[4];
#pragma unroll
  for (int j = 0; j < 4; ++j) cacc[j] = z4;
  float zl = 0.f;

  // prologue: stage sub-tile 0
#pragma unroll
  for (int it = 0; it < 4; ++it) {
    const int row = grow0 + it * 2;
    glds16(cbase + (size_t)row * C + ((ggran ^ (row & 7)) << 3),
           &cb_s[0][(w * 8 + it * 2) * 256]);
  }
  __syncthreads();

  for (int t = 0; t < 8; ++t) {
    const int cur = t & 1;
    if (t < 7) {
      const ushort* nb = cbase + (size_t)(t + 1) * 32 * C;
#pragma unroll
      for (int it = 0; it < 4; ++it) {
        const int row = grow0 + it * 2;
        glds16(nb + (size_t)row * C + ((ggran ^ (row & 7)) << 3),
               &cb_s[cur ^ 1][(w * 8 + it * 2) * 256]);
      }
    }

    // ---- K+V projection for own d-slice over 32 m ----
    f32x4 kacc[2], vacc[2];
#pragma unroll
    for (int i = 0; i < 2; ++i) { kacc[i] = z4; vacc[i] = z4; }
#pragma unroll
    for (int kk = 0; kk < 8; ++kk) {
      bf16x8 a[2];
#pragma unroll
      for (int i = 0; i < 2; ++i) {
        const int r = i * 16 + col;
        a[i] = *(const bf16x8*)(&cb_s[cur][r * 256 +
                  ((((kk << 2) + quad) ^ (r & 7)) << 3)]);
      }
      const bf16x8 wkf = *(const bf16x8*)(wkp + (size_t)kk * 32);
      const bf16x8 wvf = *(const bf16x8*)(wvp + (size_t)kk * 32);
#pragma unroll
      for (int i = 0; i < 2; ++i) {
        kacc[i] = mfma16(a[i], wkf, kacc[i]);
        vacc[i] = mfma16(a[i], wvf, vacc[i]);
      }
    }

    // ---- exp + stage P/V (own 16 d rows), Z partial ----
#pragma unroll
    for (int i = 0; i < 2; ++i) {
      const int off = (dw + col) * 32 +
                      (((i * 2 + (quad >> 1)) ^ swc) << 3) + ((quad & 1) << 2);
      const f32x4 k4 = kacc[i];
      const float e0 = __expf(k4[0]), e1 = __expf(k4[1]);
      const float e2 = __expf(k4[2]), e3 = __expf(k4[3]);
      zl += (e0 + e1) + (e2 + e3);
      ushort4 pk; pk.x = f2bf(e0); pk.y = f2bf(e1);
      pk.z = f2bf(e2); pk.w = f2bf(e3);
      *(ushort4*)(p_s + off) = pk;
      const f32x4 v4 = vacc[i];
      ushort4 vk; vk.x = f2bf(v4[0]); vk.y = f2bf(v4[1]);
      vk.z = f2bf(v4[2]); vk.w = f2bf(v4[3]);
      *(ushort4*)(v_s + off) = vk;
    }
    __syncthreads();

    // ---- PV accumulate: one K-step over this sub-tile's 32 m ----
    {
      const int g = (quad ^ swc) << 3;
      const bf16x8 pa = *(const bf16x8*)(p_s + (dw + col) * 32 + g);
      bf16x8 vb[4];
#pragma unroll
      for (int j = 0; j < 4; ++j)
        vb[j] = *(const bf16x8*)(v_s + (j * 16 + col) * 32 + g);
#pragma unroll
      for (int j = 0; j < 4; ++j) cacc[j] = mfma16(pa, vb[j], cacc[j]);
    }
    __syncthreads();   // P/V reuse + cb prefetch completion (vmcnt drain)
  }

  // ---- Z: reduce over quads (wave owns its d-slice exclusively) ----
  {
    float s = zl;
    s += __shfl_xor(s, 16); s += __shfl_xor(s, 32);
    if (quad == 0)
      z_part[((size_t)(b * H + h) * 16 + mt) * 64 + dw + col] = s;
  }

  // ---- ctx epilogue: [d][e] ----
  float* outp = ctx_part + ((size_t)(b * H + h) * 16 + mt) * 4096;
#pragma unroll
  for (int j = 0; j < 4; ++j)
#pragma unroll
    for (int r = 0; r < 4; ++r)
      outp[(size_t)(dw + quad * 4 + r) * 64 + j * 16 + col] = cacc[j][r];
}

// ---------------------------------------------------------------------------
// Kernel 2: sum partials, normalize by Z (per d = idx>>6), fold in scale.
// ctx_part / ctxn are [d][e].  Grid (B*H, 16).
// ---------------------------------------------------------------------------
__global__ __launch_bounds__(256) void combine_kernel(
    const float* __restrict__ ctx_part, const float* __restrict__ z_part,
    float* __restrict__ ctxn)            // [B*H][64(d)][64(e)]
{
  const int bh = blockIdx.x, seg = blockIdx.y, tid = threadIdx.x;
  __shared__ float zs[64];
  if (tid < 64) {
    float z = 0.f;
#pragma unroll
    for (int p = 0; p < 16; ++p) z += z_part[((size_t)bh * 16 + p) * 64 + tid];
    zs[tid] = SCALE / z;
  }
  __syncthreads();
  const int idx = (seg << 8) + tid;
  const float* cp = ctx_part + (size_t)bh * 16 * 4096;
  float s = 0.f;
#pragma unroll
  for (int p = 0; p < 16; ++p) s += cp[(size_t)p * 4096 + idx];
  ctxn[((size_t)bh << 12) + idx] = s * zs[idx >> 6];
}

// ---------------------------------------------------------------------------
// Kernel 3a: A[b][h*64+e][c] = sum_d ctxn[b,h][d][e] * Wq[h*64+d, c]   (fp32)
// Grid (B*H, 4): one 64-col c-tile per block.  ctxn [d][e] -> ct[e][d].
// ---------------------------------------------------------------------------
__global__ __launch_bounds__(256) void a_kernel(
    const float* __restrict__ ctxn, const float* __restrict__ Wq,
    float* __restrict__ A)               // [B][HID][C]
{
  const int bh = blockIdx.x, cti = blockIdx.y, tid = threadIdx.x;
  const int b = bh >> 3, h = bh & 7;
  const int c0 = cti << 6;
  __shared__ float ct[64 * 65];   // [e][d]
  __shared__ float wq[64 * 68];   // [d][c-tile]
  for (int r = 0; r < 16; ++r) {
    const int idx = tid + (r << 8);
    ct[(idx & 63) * 65 + (idx >> 6)] = ctxn[((size_t)bh << 12) + idx];
    wq[(idx >> 6) * 68 + (idx & 63)] =
        Wq[(size_t)(h * 64 + (idx >> 6)) * C + c0 + (idx & 63)];
  }
  __syncthreads();
  const int e = tid & 63, co = tid >> 6;
  float acc[16];
#pragma unroll
  for (int k = 0; k < 16; ++k) acc[k] = 0.f;
  for (int d = 0; d < 64; ++d) {
    const float cv = ct[e * 65 + d];
    const float* wr = wq + d * 68 + co * 16;
#pragma unroll
    for (int k = 0; k < 16; ++k) acc[k] += cv * wr[k];
  }
  float* Ar = A + ((size_t)b * HID + h * 64 + e) * C + c0 + co * 16;
#pragma unroll
  for (int k = 0; k < 16; ++k) Ar[k] = acc[k];
}

// ---------------------------------------------------------------------------
// Kernel 3b: M[b] = Wo (256x512) @ A[b] (512x256)  -> bf16 [b][o][c]
// 32x64 tiles, grid (32, B) = 256 blocks.
// ---------------------------------------------------------------------------
__global__ __launch_bounds__(256) void m_kernel(
    const float* __restrict__ A, const float* __restrict__ Wo,
    ushort* __restrict__ M_bf)
{
  const int tile = blockIdx.x, b = blockIdx.y;
  const int o0 = (tile & 7) << 5, c0 = (tile >> 3) << 6;
  const int tid = threadIdx.x, tx = tid & 15, ty = tid >> 4;
  __shared__ float wo_s[16 * 36];  // [k][o 32]
  __shared__ float a_s[16 * 68];   // [k][c 64]
  float acc[2][4] = {{0.f}};
  const int ow = tid >> 3, koff = (tid & 7) << 1;
  const int kk = tid >> 4, cc = (tid & 15) << 2;
  for (int k0 = 0; k0 < HID; k0 += 16) {
    __syncthreads();
    const float2 w2 = *(const float2*)(Wo + (size_t)(o0 + ow) * HID + k0 + koff);
    wo_s[(koff + 0) * 36 + ow] = w2.x;
    wo_s[(koff + 1) * 36 + ow] = w2.y;
    *(float4*)(a_s + kk * 68 + cc) =
        *(const float4*)(A + ((size_t)b * HID + k0 + kk) * C + c0 + cc);
    __syncthreads();
#pragma unroll
    for (int kc = 0; kc < 16; ++kc) {
      const float2 wv = *(const float2*)(wo_s + kc * 36 + ty * 2);
      const float4 av = *(const float4*)(a_s + kc * 68 + tx * 4);
      acc[0][0] += wv.x * av.x; acc[0][1] += wv.x * av.y;
      acc[0][2] += wv.x * av.z; acc[0][3] += wv.x * av.w;
      acc[1][0] += wv.y * av.x; acc[1][1] += wv.y * av.y;
      acc[1][2] += wv.y * av.z; acc[1][3] += wv.y * av.w;
    }
  }
#pragma unroll
  for (int i = 0; i < 2; ++i) {
    ushort4 r;
    r.x = f2bf(acc[i][0]); r.y = f2bf(acc[i][1]);
    r.z = f2bf(acc[i][2]); r.w = f2bf(acc[i][3]);
    *(ushort4*)(M_bf + ((size_t)b * C + o0 + ty * 2 + i) * C + c0 + tx * 4) = r;
  }
}

// ---------------------------------------------------------------------------
// Kernel 4 (MFMA): out[b] = M_b (256x256) @ X_b (256x4096) + bo
// o-tile 32 -> grid (16, 8, 8) = 1024 blocks, acc[2][4] = 32 regs/thread.
// ---------------------------------------------------------------------------
__global__ __launch_bounds__(256, 4) void out_mfma_kernel(
    const ushort* __restrict__ M_bf,     // [B][C][C] bf16
    const ushort* __restrict__ x_bf,     // [B][N][C] bf16
    const float* __restrict__ bo, float* __restrict__ out)
{
  const int nt = blockIdx.x, ot = blockIdx.y, b = blockIdx.z;
  const int tid = threadIdx.x;
  const int w = tid >> 6, lane = tid & 63;
  const int col = lane & 15, quad = lane >> 4;
  const int o0 = ot * 32;
  const size_t n_base = (size_t)nt * 256 + w * 64;
  const ushort* Ab = M_bf + ((size_t)b * C + o0 + col) * C + quad * 8;
  const ushort* Bb = x_bf + ((size_t)b * N + n_base) * C + quad * 8;

  const f32x4 z4 = {0.f, 0.f, 0.f, 0.f};
  f32x4 acc[2][4];
#pragma unroll
  for (int i = 0; i < 2; ++i)
#pragma unroll
    for (int j = 0; j < 4; ++j) acc[i][j] = z4;

#pragma unroll
  for (int kk = 0; kk < 8; ++kk) {
    bf16x8 af[2], bfz[4];
#pragma unroll
    for (int i = 0; i < 2; ++i)
      af[i] = *(const bf16x8*)(Ab + (size_t)(i * 16) * C + kk * 32);
#pragma unroll
    for (int j = 0; j < 4; ++j)
      bfz[j] = *(const bf16x8*)(Bb + (size_t)(j * 16 + col) * C + kk * 32);
#pragma unroll
    for (int i = 0; i < 2; ++i)
#pragma unroll
      for (int j = 0; j < 4; ++j) acc[i][j] = mfma16(af[i], bfz[j], acc[i][j]);
  }

#pragma unroll
  for (int i = 0; i < 2; ++i)
#pragma unroll
    for (int r = 0; r < 4; ++r) {
      const int o = o0 + i * 16 + quad * 4 + r;
      const float bias = bo[o];
      float* op = out + ((size_t)b * C + o) * N + n_base + col;
#pragma unroll
      for (int j = 0; j < 4; ++j) op[j * 16] = acc[i][j][r] + bias;
    }
}

// ---------------------------------------------------------------------------
extern "C" void kernel_launch(void* const* d_in, const int* in_sizes, int n_in,
                              void* d_out, int out_size, void* d_ws, size_t ws_size,
                              hipStream_t stream) {
  const float* x    = (const float*)d_in[0];
  const float* ctxt = (const float*)d_in[1];
  const float* Wq   = (const float*)d_in[2];
  const float* Wk   = (const float*)d_in[3];
  const float* Wv   = (const float*)d_in[4];
  const float* Wo   = (const float*)d_in[5];
  const float* bo   = (const float*)d_in[6];
  float* out = (float*)d_out;

  char* p = (char*)d_ws;
  ushort* ctxt_bf = (ushort*)p;  p += (size_t)B * N * C * 2;        // 16 MB
  ushort* x_bf    = (ushort*)p;  p += (size_t)B * N * C * 2;        // 16 MB
  ushort* wk_bf   = (ushort*)p;  p += (size_t)HID * C * 2;
  ushort* wv_bf   = (ushort*)p;  p += (size_t)HID * C * 2;
  ushort* M_bf    = (ushort*)p;  p += (size_t)B * C * C * 2;
  float*  z_part  = (float*)p;   p += (size_t)B * H * 16 * 64 * 4;
  float*  ctxn    = (float*)p;   p += (size_t)B * H * D * D * 4;
  float*  ctx_part= (float*)p;   p += (size_t)B * H * 16 * 4096 * 4; // 16.8 MB
  float*  A       = ctx_part;    // aliased: ctx_part dead after combine_kernel

  prep_kernel<<<dim3(N / 64, C / 64, 17), 256, 0, stream>>>(
      x, ctxt, Wk, Wv, x_bf, ctxt_bf, wk_bf, wv_bf);
  kv_mfma_kernel<<<dim3(16, H, B), 256, 0, stream>>>(ctxt_bf, wk_bf, wv_bf, ctx_part, z_part);
  combine_kernel<<<dim3(B * H, 16), 256, 0, stream>>>(ctx_part, z_part, ctxn);
  a_kernel<<<dim3(B * H, 4), 256, 0, stream>>>(ctxn, Wq, A);
  m_kernel<<<dim3(32, B), 256, 0, stream>>>(A, Wo, M_bf);
  out_mfma_kernel<<<dim3(N / 256, C / 32, B), 256, 0, stream>>>(M_bf, x_bf, bo, out);
}